// Round 9
// baseline (360.332 us; speedup 1.0000x reference)
//
#include <hip/hip_runtime.h>
#include <stdint.h>

#define B_ 8
#define C_ 32
#define N_ 4096
#define KOUT 9
#define RPB 4       // rows (centers) per block; waves 0..3 select, 4..7 assist
#define TPB 512     // 8 waves

typedef unsigned long long u64;
typedef unsigned int u32;

// monotone float->uint mapping: a<b  <=>  fkey(a)<fkey(b)
__device__ __forceinline__ u32 fkey(float f) {
    u32 u = __float_as_uint(f);
    return u ^ (u32)((((int)u) >> 31) | 0x80000000u);
}

// branchless insert of k into sorted L0<=..<=L5 (keep 6 smallest)
__device__ __forceinline__ void ins6(u64 k, u64& L0, u64& L1, u64& L2,
                                     u64& L3, u64& L4, u64& L5) {
    bool lt0 = k < L0, lt1 = k < L1, lt2 = k < L2,
         lt3 = k < L3, lt4 = k < L4, lt5 = k < L5;
    L5 = lt4 ? L4 : (lt5 ? k : L5);
    L4 = lt3 ? L3 : (lt4 ? k : L4);
    L3 = lt2 ? L2 : (lt3 ? k : L3);
    L2 = lt1 ? L1 : (lt2 ? k : L2);
    L1 = lt0 ? L0 : (lt1 ? k : L1);
    L0 = lt0 ? k : L0;
}

// sq[b,n] = np.sum(pts*pts, -1), numpy pairwise 8-acc pattern (bit-exact, proven R1)
__global__ __launch_bounds__(256) void sq_kernel(const float* __restrict__ x,
                                                 float* __restrict__ sq) {
#pragma clang fp contract(off)
    int gid = blockIdx.x * 256 + threadIdx.x;
    int b = gid >> 12, n = gid & (N_ - 1);
    const float* xp = x + (size_t)b * (C_ * N_) + n;
    float w[C_];
#pragma unroll
    for (int c = 0; c < C_; ++c) { float v = xp[(size_t)c * N_]; w[c] = v * v; }
    float r[8];
#pragma unroll
    for (int j = 0; j < 8; ++j) r[j] = w[j];
#pragma unroll
    for (int i = 8; i < 32; i += 8) {
#pragma unroll
        for (int j = 0; j < 8; ++j) r[j] = r[j] + w[i + j];
    }
    sq[gid] = ((r[0] + r[1]) + (r[2] + r[3])) + ((r[4] + r[5]) + (r[6] + r[7]));
}

__global__ __launch_bounds__(TPB, 4) void knn_kernel(const float* __restrict__ x,
                                                     const float* __restrict__ sq,
                                                     int* __restrict__ out) {
#pragma clang fp contract(off)
    __shared__ u32 distK[RPB][N_];       // 64 KB fkey keys (read-only in phase 2)
    __shared__ u64 candL[RPB][64][6];    // 12 KB helper-wave top-6 deposits
    __shared__ float cenL[C_][RPB];      // centers [c][r]

    const int tid = threadIdx.x;
    const int b = blockIdx.x & 7;               // XCD-batch affinity (proven R2)
    const int i0 = (blockIdx.x >> 3) * RPB;
    const float* xb = x + (size_t)b * (C_ * N_);
    const float* sqb = sq + b * N_;

    if (tid < RPB * C_) {
        int r = tid & (RPB - 1), c = tid >> 2;
        cenL[c][r] = xb[(size_t)c * N_ + (i0 + r)];
    }
    __syncthreads();

    const float sqi0 = sqb[i0 + 0], sqi1 = sqb[i0 + 1],
                sqi2 = sqb[i0 + 2], sqi3 = sqb[i0 + 3];

    // ---- phase 1 (R5 verbatim): thread t owns j = (g<<11) + 4t + u ----
    float acc[RPB][8];
#pragma unroll
    for (int r = 0; r < RPB; ++r)
#pragma unroll
        for (int q = 0; q < 8; ++q) acc[r][q] = 0.0f;

#pragma unroll 1
    for (int cc = 0; cc < C_; cc += 4) {
        float4 cen[4];                  // cen[e] = rows 0..3 at c=cc+e
#pragma unroll
        for (int e = 0; e < 4; ++e)
            cen[e] = *(const float4*)(&cenL[cc + e][0]);
#pragma unroll
        for (int g = 0; g < 2; ++g) {
            const int jb = (g << 11) + (tid << 2);
            float4 v[4];
#pragma unroll
            for (int e = 0; e < 4; ++e)
                v[e] = *(const float4*)(xb + (size_t)(cc + e) * N_ + jb); // dwordx4
#pragma unroll
            for (int e = 0; e < 4; ++e) {
                // numpy einsum chain: c ascending per (row, j) — bit-exactness invariant
                acc[0][(g<<2)+0] = __builtin_fmaf(cen[e].x, v[e].x, acc[0][(g<<2)+0]);
                acc[0][(g<<2)+1] = __builtin_fmaf(cen[e].x, v[e].y, acc[0][(g<<2)+1]);
                acc[0][(g<<2)+2] = __builtin_fmaf(cen[e].x, v[e].z, acc[0][(g<<2)+2]);
                acc[0][(g<<2)+3] = __builtin_fmaf(cen[e].x, v[e].w, acc[0][(g<<2)+3]);
                acc[1][(g<<2)+0] = __builtin_fmaf(cen[e].y, v[e].x, acc[1][(g<<2)+0]);
                acc[1][(g<<2)+1] = __builtin_fmaf(cen[e].y, v[e].y, acc[1][(g<<2)+1]);
                acc[1][(g<<2)+2] = __builtin_fmaf(cen[e].y, v[e].z, acc[1][(g<<2)+2]);
                acc[1][(g<<2)+3] = __builtin_fmaf(cen[e].y, v[e].w, acc[1][(g<<2)+3]);
                acc[2][(g<<2)+0] = __builtin_fmaf(cen[e].z, v[e].x, acc[2][(g<<2)+0]);
                acc[2][(g<<2)+1] = __builtin_fmaf(cen[e].z, v[e].y, acc[2][(g<<2)+1]);
                acc[2][(g<<2)+2] = __builtin_fmaf(cen[e].z, v[e].z, acc[2][(g<<2)+2]);
                acc[2][(g<<2)+3] = __builtin_fmaf(cen[e].z, v[e].w, acc[2][(g<<2)+3]);
                acc[3][(g<<2)+0] = __builtin_fmaf(cen[e].w, v[e].x, acc[3][(g<<2)+0]);
                acc[3][(g<<2)+1] = __builtin_fmaf(cen[e].w, v[e].y, acc[3][(g<<2)+1]);
                acc[3][(g<<2)+2] = __builtin_fmaf(cen[e].w, v[e].z, acc[3][(g<<2)+2]);
                acc[3][(g<<2)+3] = __builtin_fmaf(cen[e].w, v[e].w, acc[3][(g<<2)+3]);
            }
        }
    }

    // ---- epilogue: finish distances, write fkey keys to distK (b128 stores) ----
#pragma unroll
    for (int g = 0; g < 2; ++g) {
        const int jb = (g << 11) + (tid << 2);
        float4 sj = *(const float4*)(sqb + jb);
#pragma unroll
        for (int r = 0; r < RPB; ++r) {
            const float sqi = (r == 0) ? sqi0 : (r == 1) ? sqi1 : (r == 2) ? sqi2 : sqi3;
            // (sq_i - 2*inner) + sq_j, each op rounded once (contract off)
            uint4 k4;
            k4.x = fkey((sqi - 2.0f * acc[r][(g<<2)+0]) + sj.x);
            k4.y = fkey((sqi - 2.0f * acc[r][(g<<2)+1]) + sj.y);
            k4.z = fkey((sqi - 2.0f * acc[r][(g<<2)+2]) + sj.z);
            k4.w = fkey((sqi - 2.0f * acc[r][(g<<2)+3]) + sj.w);
            *(uint4*)(&distK[r][jb]) = k4;
        }
    }
    __syncthreads();

    // ---- phase 2a: split scan. Wave w scans m=0..31 of row w; wave w+4 scans
    // m=32..63 of row w and deposits its per-lane top-6 to candL. Merged list
    // (top-6 of union of half-top-6s) = exact per-lane top-6 over all 64 m.
    const int wv = tid >> 6, lane = tid & 63;
    const int w = wv & (RPB - 1);
    const u32* drow = distK[w];

    u64 L0 = ~0ull, L1 = ~0ull, L2 = ~0ull, L3 = ~0ull, L4 = ~0ull, L5 = ~0ull;
    {
        const int mBase = (wv < RPB) ? 0 : 32;
#pragma unroll 4
        for (int m = 0; m < 32; ++m) {
            int j = lane + ((m + mBase) << 6);    // owner(j)=j&63, 2-way alias free
            u64 kk = ((u64)drow[j] << 32) | (u32)j;
            ins6(kk, L0, L1, L2, L3, L4, L5);
        }
    }
    if (wv >= RPB) {
        u64* c = candL[w][lane];
        c[0] = L0; c[1] = L1; c[2] = L2; c[3] = L3; c[4] = L4; c[5] = L5;
    }
    __syncthreads();

    // ---- phase 2b: waves 0..3 merge + 9 pop-2 rounds ----
    if (wv < RPB) {
        {
            const u64* c = candL[w][lane];
#pragma unroll
            for (int k = 0; k < 6; ++k) ins6(c[k], L0, L1, L2, L3, L4, L5);
        }

        u64 lastPop = 0;
        u32 myw = 0;
#pragma unroll 1
        for (int r = 0; r < KOUT; ++r) {       // 9 rounds x 2 pops = 18 >= 17
            // butterfly min-2 of all lanes' (L0, L1)
            u64 a0 = L0, a1 = L1;
#pragma unroll
            for (int off = 32; off >= 1; off >>= 1) {
                u64 b0 = __shfl_xor(a0, off);
                u64 b1 = __shfl_xor(a1, off);
                u64 lo = (a0 < b0) ? a0 : b0;
                u64 hi = (a0 < b0) ? b0 : a0;
                u64 m1 = (a1 < b1) ? a1 : b1;
                a0 = lo;
                a1 = (hi < m1) ? hi : m1;
            }
            // a0 = sorted position 2r -> output slot r; a1 = position 2r+1 (discard)
            if (lane == r) myw = (u32)a0;

            // consume both winners from their owners' lists
            bool own0 = ((u32)a0 & 63) == (u32)lane;
            bool own1 = ((u32)a1 & 63) == (u32)lane;
            if (own0) { lastPop = a0; L0 = L1; L1 = L2; L2 = L3; L3 = L4; L4 = L5; L5 = ~0ull; }
            if (own1) { lastPop = a1; L0 = L1; L1 = L2; L2 = L3; L3 = L4; L4 = L5; L5 = ~0ull; }
            // REBUILD when <2 valid remain (exposure invariant, R6 lesson). All my
            // unpopped owned keys are > lastPop, so a fresh filtered rescan is exact.
            if ((own0 || own1) && L1 == ~0ull && r < KOUT - 1) {
                L0 = L1 = L2 = L3 = L4 = L5 = ~0ull;
#pragma unroll 1
                for (int m = 0; m < 64; ++m) {
                    int j = lane + (m << 6);
                    u64 kk = ((u64)drow[j] << 32) | (u32)j;
                    if (kk > lastPop) ins6(kk, L0, L1, L2, L3, L4, L5);
                }
            }
        }

        // ---- output: (2, B, N, KOUT) int32 ----
        if (lane < KOUT) {
            int row = b * N_ + i0 + w;
            int o = row * KOUT + lane;
            out[o] = (int)(myw & (N_ - 1));    // j of sorted position 2*lane
            out[B_ * N_ * KOUT + o] = i0 + w;  // center index
        }
    }
}

extern "C" void kernel_launch(void* const* d_in, const int* in_sizes, int n_in,
                              void* d_out, int out_size, void* d_ws, size_t ws_size,
                              hipStream_t stream) {
    const float* x = (const float*)d_in[0];
    float* sq = (float*)d_ws;            // B*N floats = 128 KB
    int* out = (int*)d_out;

    hipLaunchKernelGGL(sq_kernel, dim3(B_ * N_ / 256), dim3(256), 0, stream, x, sq);
    hipLaunchKernelGGL(knn_kernel, dim3(B_ * N_ / RPB), dim3(TPB), 0, stream, x, sq, out);
}

// Round 10
// 253.588 us; speedup vs baseline: 1.4209x; 1.4209x over previous
//
#include <hip/hip_runtime.h>
#include <stdint.h>

#define B_ 8
#define C_ 32
#define N_ 4096
#define KOUT 9
#define RPB 4       // rows (centers) per block; waves 0..3 each select one row
#define TPB 512     // 8 waves

typedef unsigned long long u64;
typedef unsigned int u32;

// monotone float->uint mapping: a<b  <=>  fkey(a)<fkey(b)
__device__ __forceinline__ u32 fkey(float f) {
    u32 u = __float_as_uint(f);
    return u ^ (u32)((((int)u) >> 31) | 0x80000000u);
}

// branchless insert of k into sorted L0<=..<=L5 (keep 6 smallest) — fallback path
__device__ __forceinline__ void ins6(u64 k, u64& L0, u64& L1, u64& L2,
                                     u64& L3, u64& L4, u64& L5) {
    bool lt0 = k < L0, lt1 = k < L1, lt2 = k < L2,
         lt3 = k < L3, lt4 = k < L4, lt5 = k < L5;
    L5 = lt4 ? L4 : (lt5 ? k : L5);
    L4 = lt3 ? L3 : (lt4 ? k : L4);
    L3 = lt2 ? L2 : (lt3 ? k : L3);
    L2 = lt1 ? L1 : (lt2 ? k : L2);
    L1 = lt0 ? L0 : (lt1 ? k : L1);
    L0 = lt0 ? k : L0;
}

// sq[b,n] = np.sum(pts*pts, -1), numpy pairwise 8-acc pattern (bit-exact, proven R1)
__global__ __launch_bounds__(256) void sq_kernel(const float* __restrict__ x,
                                                 float* __restrict__ sq) {
#pragma clang fp contract(off)
    int gid = blockIdx.x * 256 + threadIdx.x;
    int b = gid >> 12, n = gid & (N_ - 1);
    const float* xp = x + (size_t)b * (C_ * N_) + n;
    float w[C_];
#pragma unroll
    for (int c = 0; c < C_; ++c) { float v = xp[(size_t)c * N_]; w[c] = v * v; }
    float r[8];
#pragma unroll
    for (int j = 0; j < 8; ++j) r[j] = w[j];
#pragma unroll
    for (int i = 8; i < 32; i += 8) {
#pragma unroll
        for (int j = 0; j < 8; ++j) r[j] = r[j] + w[i + j];
    }
    sq[gid] = ((r[0] + r[1]) + (r[2] + r[3])) + ((r[4] + r[5]) + (r[6] + r[7]));
}

__global__ __launch_bounds__(TPB, 4) void knn_kernel(const float* __restrict__ x,
                                                     const float* __restrict__ sq,
                                                     int* __restrict__ out) {
#pragma clang fp contract(off)
    __shared__ u32 distK[RPB][N_];       // 64 KB fkey keys (read-only in phase 2)
    __shared__ float cenL[C_][RPB];      // centers [c][r]
    __shared__ u64 bufL[RPB][64];        // candidate buffer (keys <= T)
    __shared__ u32 cntL[RPB];            // candidate counts

    const int tid = threadIdx.x;
    const int b = blockIdx.x & 7;               // XCD-batch affinity (proven R2)
    const int i0 = (blockIdx.x >> 3) * RPB;
    const float* xb = x + (size_t)b * (C_ * N_);
    const float* sqb = sq + b * N_;

    if (tid < RPB * C_) {
        int r = tid & (RPB - 1), c = tid >> 2;
        cenL[c][r] = xb[(size_t)c * N_ + (i0 + r)];
    }
    __syncthreads();

    const float sqi0 = sqb[i0 + 0], sqi1 = sqb[i0 + 1],
                sqi2 = sqb[i0 + 2], sqi3 = sqb[i0 + 3];

    // ---- phase 1 (R5 verbatim): thread t owns j = (g<<11) + 4t + u ----
    float acc[RPB][8];
#pragma unroll
    for (int r = 0; r < RPB; ++r)
#pragma unroll
        for (int q = 0; q < 8; ++q) acc[r][q] = 0.0f;

#pragma unroll 1
    for (int cc = 0; cc < C_; cc += 4) {
        float4 cen[4];                  // cen[e] = rows 0..3 at c=cc+e
#pragma unroll
        for (int e = 0; e < 4; ++e)
            cen[e] = *(const float4*)(&cenL[cc + e][0]);
#pragma unroll
        for (int g = 0; g < 2; ++g) {
            const int jb = (g << 11) + (tid << 2);
            float4 v[4];
#pragma unroll
            for (int e = 0; e < 4; ++e)
                v[e] = *(const float4*)(xb + (size_t)(cc + e) * N_ + jb); // dwordx4
#pragma unroll
            for (int e = 0; e < 4; ++e) {
                // numpy einsum chain: c ascending per (row, j) — bit-exactness invariant
                acc[0][(g<<2)+0] = __builtin_fmaf(cen[e].x, v[e].x, acc[0][(g<<2)+0]);
                acc[0][(g<<2)+1] = __builtin_fmaf(cen[e].x, v[e].y, acc[0][(g<<2)+1]);
                acc[0][(g<<2)+2] = __builtin_fmaf(cen[e].x, v[e].z, acc[0][(g<<2)+2]);
                acc[0][(g<<2)+3] = __builtin_fmaf(cen[e].x, v[e].w, acc[0][(g<<2)+3]);
                acc[1][(g<<2)+0] = __builtin_fmaf(cen[e].y, v[e].x, acc[1][(g<<2)+0]);
                acc[1][(g<<2)+1] = __builtin_fmaf(cen[e].y, v[e].y, acc[1][(g<<2)+1]);
                acc[1][(g<<2)+2] = __builtin_fmaf(cen[e].y, v[e].z, acc[1][(g<<2)+2]);
                acc[1][(g<<2)+3] = __builtin_fmaf(cen[e].y, v[e].w, acc[1][(g<<2)+3]);
                acc[2][(g<<2)+0] = __builtin_fmaf(cen[e].z, v[e].x, acc[2][(g<<2)+0]);
                acc[2][(g<<2)+1] = __builtin_fmaf(cen[e].z, v[e].y, acc[2][(g<<2)+1]);
                acc[2][(g<<2)+2] = __builtin_fmaf(cen[e].z, v[e].z, acc[2][(g<<2)+2]);
                acc[2][(g<<2)+3] = __builtin_fmaf(cen[e].z, v[e].w, acc[2][(g<<2)+3]);
                acc[3][(g<<2)+0] = __builtin_fmaf(cen[e].w, v[e].x, acc[3][(g<<2)+0]);
                acc[3][(g<<2)+1] = __builtin_fmaf(cen[e].w, v[e].y, acc[3][(g<<2)+1]);
                acc[3][(g<<2)+2] = __builtin_fmaf(cen[e].w, v[e].z, acc[3][(g<<2)+2]);
                acc[3][(g<<2)+3] = __builtin_fmaf(cen[e].w, v[e].w, acc[3][(g<<2)+3]);
            }
        }
    }

    // ---- epilogue: finish distances, write fkey keys to distK (b128 stores) ----
#pragma unroll
    for (int g = 0; g < 2; ++g) {
        const int jb = (g << 11) + (tid << 2);
        float4 sj = *(const float4*)(sqb + jb);
#pragma unroll
        for (int r = 0; r < RPB; ++r) {
            const float sqi = (r == 0) ? sqi0 : (r == 1) ? sqi1 : (r == 2) ? sqi2 : sqi3;
            // (sq_i - 2*inner) + sq_j, each op rounded once (contract off)
            uint4 k4;
            k4.x = fkey((sqi - 2.0f * acc[r][(g<<2)+0]) + sj.x);
            k4.y = fkey((sqi - 2.0f * acc[r][(g<<2)+1]) + sj.y);
            k4.z = fkey((sqi - 2.0f * acc[r][(g<<2)+2]) + sj.z);
            k4.w = fkey((sqi - 2.0f * acc[r][(g<<2)+3]) + sj.w);
            *(uint4*)(&distK[r][jb]) = k4;
        }
    }
    __syncthreads();

    // ---- phase 2: threshold filter + tiny sort (exact) ----
    const int wv = tid >> 6, lane = tid & 63;
    if (wv < RPB) {
        const int w = wv;
        const u32* drow = distK[w];
        const int row = b * N_ + i0 + w;

        // scan A: per-lane min fkey over 64 keys (uint4 loads)
        u32 mn = 0xFFFFFFFFu;
#pragma unroll 4
        for (int m = 0; m < 16; ++m) {
            uint4 k4 = *(const uint4*)(&drow[(lane + (m << 6)) << 2]);
            mn = min(mn, min(min(k4.x, k4.y), min(k4.z, k4.w)));
        }

        // bitonic sort the 64 lane-minima (u32, ascending across lanes)
        u32 v32 = mn;
#pragma unroll
        for (int k = 2; k <= 64; k <<= 1) {
#pragma unroll
            for (int j = k >> 1; j >= 1; j >>= 1) {
                u32 pv = __shfl_xor(v32, j);
                bool keepMin = (((lane & j) == 0) == ((lane & k) == 0));
                u32 lo = v32 < pv ? v32 : pv;
                u32 hi = v32 < pv ? pv : v32;
                v32 = keepMin ? lo : hi;
            }
        }
        // T = 18th-smallest lane-min. Guarantee: any key with fkey > T has >=18
        // strictly-smaller keys (the 18 lane minima <= T, distinct j) -> rank
        // >= 18 -> not in top-17. So top-17 subset of {fkey <= T}; count >= 18.
        u32 T = __shfl(v32, 17);

        if (lane == 0) cntL[w] = 0;
        // scan B: append every key <= T (wave-local LDS atomic; DS ops of one
        // wave execute in program order, so the cnt reset precedes appends)
#pragma unroll 4
        for (int m = 0; m < 16; ++m) {
            int jb = (lane + (m << 6)) << 2;
            uint4 k4 = *(const uint4*)(&drow[jb]);
            if (k4.x <= T) { u32 s = atomicAdd(&cntL[w], 1u); if (s < 64) bufL[w][s] = ((u64)k4.x << 32) | (u32)(jb + 0); }
            if (k4.y <= T) { u32 s = atomicAdd(&cntL[w], 1u); if (s < 64) bufL[w][s] = ((u64)k4.y << 32) | (u32)(jb + 1); }
            if (k4.z <= T) { u32 s = atomicAdd(&cntL[w], 1u); if (s < 64) bufL[w][s] = ((u64)k4.z << 32) | (u32)(jb + 3 - 1); }
            if (k4.w <= T) { u32 s = atomicAdd(&cntL[w], 1u); if (s < 64) bufL[w][s] = ((u64)k4.w << 32) | (u32)(jb + 3); }
        }
        u32 cnt = cntL[w];                 // program-order read after appends

        if (cnt <= 64) {
            // bitonic sort <=64 candidates (packed (fkey,j), pad ~0) ascending
            u64 v = (lane < (int)cnt) ? bufL[w][lane] : ~0ull;
#pragma unroll
            for (int k = 2; k <= 64; k <<= 1) {
#pragma unroll
                for (int j = k >> 1; j >= 1; j >>= 1) {
                    u64 pv = __shfl_xor(v, j);
                    bool keepMin = (((lane & j) == 0) == ((lane & k) == 0));
                    u64 lo = v < pv ? v : pv;
                    u64 hi = v < pv ? pv : v;
                    v = keepMin ? lo : hi;
                }
            }
            // lane p holds p-th smallest; dilated output = positions 0,2,...,16
            if ((lane & 1) == 0 && lane <= 16)
                out[row * KOUT + (lane >> 1)] = (int)((u32)v & (N_ - 1));
            if (lane < KOUT)
                out[B_ * N_ * KOUT + row * KOUT + lane] = i0 + w;
        } else {
            // ---- fallback (adversarial-only): R7 proven scan + pop-2 path ----
            u64 L0 = ~0ull, L1 = ~0ull, L2 = ~0ull, L3 = ~0ull, L4 = ~0ull, L5 = ~0ull;
#pragma unroll 4
            for (int m = 0; m < 64; ++m) {
                int j = lane + (m << 6);
                u64 kk = ((u64)drow[j] << 32) | (u32)j;
                ins6(kk, L0, L1, L2, L3, L4, L5);
            }
            u64 lastPop = 0;
            u32 myw = 0;
#pragma unroll 1
            for (int r = 0; r < KOUT; ++r) {
                u64 a0 = L0, a1 = L1;
#pragma unroll
                for (int off = 32; off >= 1; off >>= 1) {
                    u64 b0 = __shfl_xor(a0, off);
                    u64 b1 = __shfl_xor(a1, off);
                    u64 lo = (a0 < b0) ? a0 : b0;
                    u64 hi = (a0 < b0) ? b0 : a0;
                    u64 m1 = (a1 < b1) ? a1 : b1;
                    a0 = lo;
                    a1 = (hi < m1) ? hi : m1;
                }
                if (lane == r) myw = (u32)a0;
                bool own0 = ((u32)a0 & 63) == (u32)lane;
                bool own1 = ((u32)a1 & 63) == (u32)lane;
                if (own0) { lastPop = a0; L0 = L1; L1 = L2; L2 = L3; L3 = L4; L4 = L5; L5 = ~0ull; }
                if (own1) { lastPop = a1; L0 = L1; L1 = L2; L2 = L3; L3 = L4; L4 = L5; L5 = ~0ull; }
                if ((own0 || own1) && L1 == ~0ull && r < KOUT - 1) {
                    L0 = L1 = L2 = L3 = L4 = L5 = ~0ull;
#pragma unroll 1
                    for (int m = 0; m < 64; ++m) {
                        int j = lane + (m << 6);
                        u64 kk = ((u64)drow[j] << 32) | (u32)j;
                        if (kk > lastPop) ins6(kk, L0, L1, L2, L3, L4, L5);
                    }
                }
            }
            if (lane < KOUT) {
                int o = row * KOUT + lane;
                out[o] = (int)(myw & (N_ - 1));
                out[B_ * N_ * KOUT + o] = i0 + w;
            }
        }
    }
}

extern "C" void kernel_launch(void* const* d_in, const int* in_sizes, int n_in,
                              void* d_out, int out_size, void* d_ws, size_t ws_size,
                              hipStream_t stream) {
    const float* x = (const float*)d_in[0];
    float* sq = (float*)d_ws;            // B*N floats = 128 KB
    int* out = (int*)d_out;

    hipLaunchKernelGGL(sq_kernel, dim3(B_ * N_ / 256), dim3(256), 0, stream, x, sq);
    hipLaunchKernelGGL(knn_kernel, dim3(B_ * N_ / RPB), dim3(TPB), 0, stream, x, sq, out);
}

// Round 11
// 213.150 us; speedup vs baseline: 1.6905x; 1.1897x over previous
//
#include <hip/hip_runtime.h>
#include <stdint.h>

#define B_ 8
#define C_ 32
#define N_ 4096
#define KOUT 9
#define RPB 8       // rows (centers) per block; wave w selects row w
#define TPB 512     // 8 waves

typedef unsigned long long u64;
typedef unsigned int u32;

// monotone float->uint mapping: a<b  <=>  fkey(a)<fkey(b)
__device__ __forceinline__ u32 fkey(float f) {
    u32 u = __float_as_uint(f);
    return u ^ (u32)((((int)u) >> 31) | 0x80000000u);
}

// branchless insert of k into sorted L0<=..<=L5 (keep 6 smallest) — fallback only
__device__ __forceinline__ void ins6(u64 k, u64& L0, u64& L1, u64& L2,
                                     u64& L3, u64& L4, u64& L5) {
    bool lt0 = k < L0, lt1 = k < L1, lt2 = k < L2,
         lt3 = k < L3, lt4 = k < L4, lt5 = k < L5;
    L5 = lt4 ? L4 : (lt5 ? k : L5);
    L4 = lt3 ? L3 : (lt4 ? k : L4);
    L3 = lt2 ? L2 : (lt3 ? k : L3);
    L2 = lt1 ? L1 : (lt2 ? k : L2);
    L1 = lt0 ? L0 : (lt1 ? k : L1);
    L0 = lt0 ? k : L0;
}

// sq[b,n] = np.sum(pts*pts, -1), numpy pairwise 8-acc pattern (bit-exact, proven R1)
__global__ __launch_bounds__(256) void sq_kernel(const float* __restrict__ x,
                                                 float* __restrict__ sq) {
#pragma clang fp contract(off)
    int gid = blockIdx.x * 256 + threadIdx.x;
    int b = gid >> 12, n = gid & (N_ - 1);
    const float* xp = x + (size_t)b * (C_ * N_) + n;
    float w[C_];
#pragma unroll
    for (int c = 0; c < C_; ++c) { float v = xp[(size_t)c * N_]; w[c] = v * v; }
    float r[8];
#pragma unroll
    for (int j = 0; j < 8; ++j) r[j] = w[j];
#pragma unroll
    for (int i = 8; i < 32; i += 8) {
#pragma unroll
        for (int j = 0; j < 8; ++j) r[j] = r[j] + w[i + j];
    }
    sq[gid] = ((r[0] + r[1]) + (r[2] + r[3])) + ((r[4] + r[5]) + (r[6] + r[7]));
}

__global__ __launch_bounds__(TPB, 4) void knn_kernel(const float* __restrict__ x,
                                                     const float* __restrict__ sq,
                                                     int* __restrict__ out) {
#pragma clang fp contract(off)
    __shared__ float cenL[C_][RPB];      // 1 KB centers [c][r]
    __shared__ u32 mL[RPB][8][64];       // 16 KB per-(row, src-wave, lane) min key
    __shared__ u64 bufL[RPB][64];        // 4 KB candidate buffers
    __shared__ u32 cntL[RPB];
    __shared__ u32 tL[RPB];

    const int tid = threadIdx.x;
    const int b = blockIdx.x & 7;               // XCD-batch affinity (proven R2)
    const int i0 = (blockIdx.x >> 3) * RPB;
    const float* xb = x + (size_t)b * (C_ * N_);
    const float* sqb = sq + b * N_;

    if (tid < RPB * C_) {
        int r = tid & (RPB - 1), c = tid >> 3;
        cenL[c][r] = xb[(size_t)c * N_ + (i0 + r)];
    }
    __syncthreads();

    // ---- phase 1: thread t owns j(q) = ((q>>2)<<11) + 4t + (q&3), q=0..7 ----
    float acc[RPB][8];                   // [row][q], all indices static
#pragma unroll
    for (int r = 0; r < RPB; ++r)
#pragma unroll
        for (int q = 0; q < 8; ++q) acc[r][q] = 0.0f;

    const int j0 = tid << 2;
#pragma unroll 1
    for (int cc = 0; cc < C_; cc += 4) {
        float4 v0[4], v1[4];             // hoisted loads: 8 b128 in flight
#pragma unroll
        for (int e = 0; e < 4; ++e) {
            const float* xc = xb + (size_t)(cc + e) * N_;
            v0[e] = *(const float4*)(xc + j0);
            v1[e] = *(const float4*)(xc + 2048 + j0);
        }
#pragma unroll
        for (int e = 0; e < 4; ++e) {
            float4 cA = *(const float4*)(&cenL[cc + e][0]);
            float4 cB = *(const float4*)(&cenL[cc + e][4]);
            float ce[8] = {cA.x, cA.y, cA.z, cA.w, cB.x, cB.y, cB.z, cB.w};
            float vv[8] = {v0[e].x, v0[e].y, v0[e].z, v0[e].w,
                           v1[e].x, v1[e].y, v1[e].z, v1[e].w};
            // numpy einsum chain: c ascending per (row, j) — bit-exactness invariant
#pragma unroll
            for (int r = 0; r < RPB; ++r)
#pragma unroll
                for (int q = 0; q < 8; ++q)
                    acc[r][q] = __builtin_fmaf(ce[r], vv[q], acc[r][q]);
        }
    }

    // ---- epilogue: keys in registers; (sq_i - 2*inner) + sq_j, ops rounded once ----
    const int wv = tid >> 6, lane = tid & 63;
    u32 key[RPB][8];
    {
        float4 s0 = *(const float4*)(sqb + j0);
        float4 s1 = *(const float4*)(sqb + 2048 + j0);
        float sj[8] = {s0.x, s0.y, s0.z, s0.w, s1.x, s1.y, s1.z, s1.w};
#pragma unroll
        for (int r = 0; r < RPB; ++r) {
            float sqi = sqb[i0 + r];
#pragma unroll
            for (int q = 0; q < 8; ++q)
                key[r][q] = fkey((sqi - 2.0f * acc[r][q]) + sj[q]);
        }
    }

    // per-thread per-row min -> mL
#pragma unroll
    for (int r = 0; r < RPB; ++r) {
        u32 mn = key[r][0];
#pragma unroll
        for (int q = 1; q < 8; ++q) mn = min(mn, key[r][q]);
        mL[r][wv][lane] = mn;
    }
    if (tid < RPB) cntL[tid] = 0;
    __syncthreads();

    // ---- T for row wv: partition(lane) = 8 threads x 8 j = 64 j's.
    // T = 18th-smallest partition min => >=18 distinct keys <= T => top-17
    // subset of {key <= T}. (Proven exact in R9.)
    {
        u32 mn = mL[wv][0][lane];
#pragma unroll
        for (int s = 1; s < 8; ++s) mn = min(mn, mL[wv][s][lane]);
        u32 v32 = mn;
#pragma unroll
        for (int k = 2; k <= 64; k <<= 1) {
#pragma unroll
            for (int j = k >> 1; j >= 1; j >>= 1) {
                u32 pv = __shfl_xor(v32, j);
                bool keepMin = (((lane & j) == 0) == ((lane & k) == 0));
                u32 lo = v32 < pv ? v32 : pv;
                u32 hi = v32 < pv ? pv : v32;
                v32 = keepMin ? lo : hi;
            }
        }
        if (lane == 17) tL[wv] = v32;    // sorted[17] lives in lane 17
    }
    __syncthreads();

    // ---- scan B: append register keys <= T[r] to bufL[r] ----
    {
        u32 Tr[RPB];
#pragma unroll
        for (int r = 0; r < RPB; ++r) Tr[r] = tL[r];
#pragma unroll
        for (int r = 0; r < RPB; ++r) {
#pragma unroll
            for (int q = 0; q < 8; ++q) {
                if (key[r][q] <= Tr[r]) {
                    int jq = ((q >> 2) << 11) + j0 + (q & 3);
                    u32 s = atomicAdd(&cntL[r], 1u);
                    if (s < 64) bufL[r][s] = ((u64)key[r][q] << 32) | (u32)jq;
                }
            }
        }
    }
    __syncthreads();

    // ---- wave wv: sort candidates of row wv, write dilated output ----
    {
        const int w = wv;
        const u32 cnt = cntL[w];
        const int row = b * N_ + i0 + w;
        if (cnt <= 64) {
            u64 v = (lane < (int)cnt) ? bufL[w][lane] : ~0ull;
#pragma unroll
            for (int k = 2; k <= 64; k <<= 1) {
#pragma unroll
                for (int j = k >> 1; j >= 1; j >>= 1) {
                    u64 pv = __shfl_xor(v, j);
                    bool keepMin = (((lane & j) == 0) == ((lane & k) == 0));
                    u64 lo = v < pv ? v : pv;
                    u64 hi = v < pv ? pv : v;
                    v = keepMin ? lo : hi;
                }
            }
            if ((lane & 1) == 0 && lane <= 16)
                out[row * KOUT + (lane >> 1)] = (int)((u32)v & (N_ - 1));
            if (lane < KOUT)
                out[B_ * N_ * KOUT + row * KOUT + lane] = i0 + w;
        } else {
            // ---- fallback (P ~ e^-21 per row): recompute row bit-exactly + R7 pop-2 ----
            const float sqw = sqb[i0 + w];
            u64 L0 = ~0ull, L1 = ~0ull, L2 = ~0ull, L3 = ~0ull, L4 = ~0ull, L5 = ~0ull;
#pragma unroll 1
            for (int m = 0; m < 64; ++m) {
                int j = lane + (m << 6);
                float a = 0.0f;
#pragma unroll 1
                for (int c = 0; c < C_; ++c)
                    a = __builtin_fmaf(cenL[c][w], xb[(size_t)c * N_ + j], a);
                float d = (sqw - 2.0f * a) + sqb[j];
                ins6(((u64)fkey(d) << 32) | (u32)j, L0, L1, L2, L3, L4, L5);
            }
            u64 lastPop = 0;
            u32 myw = 0;
#pragma unroll 1
            for (int r = 0; r < KOUT; ++r) {
                u64 a0 = L0, a1 = L1;
#pragma unroll
                for (int off = 32; off >= 1; off >>= 1) {
                    u64 b0 = __shfl_xor(a0, off);
                    u64 b1 = __shfl_xor(a1, off);
                    u64 lo = (a0 < b0) ? a0 : b0;
                    u64 hi = (a0 < b0) ? b0 : a0;
                    u64 m1 = (a1 < b1) ? a1 : b1;
                    a0 = lo;
                    a1 = (hi < m1) ? hi : m1;
                }
                if (lane == r) myw = (u32)a0;
                bool own0 = ((u32)a0 & 63) == (u32)lane;
                bool own1 = ((u32)a1 & 63) == (u32)lane;
                if (own0) { lastPop = a0; L0 = L1; L1 = L2; L2 = L3; L3 = L4; L4 = L5; L5 = ~0ull; }
                if (own1) { lastPop = a1; L0 = L1; L1 = L2; L2 = L3; L3 = L4; L4 = L5; L5 = ~0ull; }
                if ((own0 || own1) && L1 == ~0ull && r < KOUT - 1) {
                    L0 = L1 = L2 = L3 = L4 = L5 = ~0ull;
#pragma unroll 1
                    for (int m = 0; m < 64; ++m) {
                        int j = lane + (m << 6);
                        float a = 0.0f;
#pragma unroll 1
                        for (int c = 0; c < C_; ++c)
                            a = __builtin_fmaf(cenL[c][w], xb[(size_t)c * N_ + j], a);
                        float d = (sqw - 2.0f * a) + sqb[j];
                        u64 kk = ((u64)fkey(d) << 32) | (u32)j;
                        if (kk > lastPop) ins6(kk, L0, L1, L2, L3, L4, L5);
                    }
                }
            }
            if (lane < KOUT) {
                int o = row * KOUT + lane;
                out[o] = (int)(myw & (N_ - 1));
                out[B_ * N_ * KOUT + o] = i0 + w;
            }
        }
    }
}

extern "C" void kernel_launch(void* const* d_in, const int* in_sizes, int n_in,
                              void* d_out, int out_size, void* d_ws, size_t ws_size,
                              hipStream_t stream) {
    const float* x = (const float*)d_in[0];
    float* sq = (float*)d_ws;            // B*N floats = 128 KB
    int* out = (int*)d_out;

    hipLaunchKernelGGL(sq_kernel, dim3(B_ * N_ / 256), dim3(256), 0, stream, x, sq);
    hipLaunchKernelGGL(knn_kernel, dim3(B_ * N_ / RPB), dim3(TPB), 0, stream, x, sq, out);
}